// Round 5
// baseline (103.689 us; speedup 1.0000x reference)
//
#include <hip/hip_runtime.h>
#include <hip/hip_bf16.h>
#include <cstdint>

#define IN_DIM 256
#define OUT_DIM 128
#define CAP 192   // max edges per target row; Poisson(64) -> P(>192) ~ e^-40

typedef __attribute__((ext_vector_type(8))) short short8;
typedef __attribute__((ext_vector_type(4))) float f32x4;

__device__ __forceinline__ unsigned short f2bf(float f) {
    __hip_bfloat16 b = __float2bfloat16(f);
    return *reinterpret_cast<unsigned short*>(&b);
}
__device__ __forceinline__ float bf2f(unsigned short u) {
    union { unsigned int i; float f; } v;
    v.i = ((unsigned int)u) << 16;
    return v.f;
}

// ---------------- one-time: Wt[n][k] = bf16(W[k][n]); also zero cursor ----------------
__global__ __launch_bounds__(256) void wt_kernel(const float* __restrict__ Wm,
                                                 unsigned short* __restrict__ Wt,
                                                 int* __restrict__ cursor, int T) {
    const int idx = blockIdx.x * 256 + threadIdx.x;   // 256*128 = 32768
    const int k = idx >> 7;
    const int n = idx & 127;
    Wt[n * 256 + k] = f2bf(Wm[idx]);
    if (idx < T) cursor[idx] = 0;
}

// ---------------- GEMM: Hb = bf16(features @ W), fused s1/s2 ----------------
// LDS-free, barrier-free. 1 wave per block; block covers 16 rows x 128 cols.
// A fragments loaded global->reg (fp32->bf16 in flight); B fragments from
// L2-resident Wt (64 KB, shared by all blocks). 8 MFMA per K-step, 8 steps.
__global__ __launch_bounds__(64) void gemm_h(const float* __restrict__ A,
                                             const unsigned short* __restrict__ Wt,
                                             const float* __restrict__ av,
                                             unsigned short* __restrict__ Hb,
                                             float* __restrict__ s1,
                                             float* __restrict__ s2, int Nn) {
    const int lane = threadIdx.x;
    const int l15 = lane & 15;
    const int lhi = lane >> 4;
    const int bm  = blockIdx.x * 16;

    int ar = bm + l15;
    if (ar >= Nn) ar = Nn - 1;               // clamp: safe read, stores guarded
    const float* Arow = A + (size_t)ar * IN_DIM + lhi * 8;
    const unsigned short* Wb = Wt + l15 * IN_DIM + lhi * 8;

    f32x4 acc[8];
    #pragma unroll
    for (int j = 0; j < 8; ++j) acc[j] = (f32x4){0.f, 0.f, 0.f, 0.f};

    #pragma unroll
    for (int ks = 0; ks < 8; ++ks) {
        const float4 f0 = *(const float4*)(Arow + ks * 32);
        const float4 f1 = *(const float4*)(Arow + ks * 32 + 4);
        short8 a;
        a[0] = (short)f2bf(f0.x); a[1] = (short)f2bf(f0.y);
        a[2] = (short)f2bf(f0.z); a[3] = (short)f2bf(f0.w);
        a[4] = (short)f2bf(f1.x); a[5] = (short)f2bf(f1.y);
        a[6] = (short)f2bf(f1.z); a[7] = (short)f2bf(f1.w);
        #pragma unroll
        for (int j = 0; j < 8; ++j) {
            const short8 b = *(const short8*)(Wb + (size_t)j * 16 * IN_DIM + ks * 32);
            acc[j] = __builtin_amdgcn_mfma_f32_16x16x32_bf16(a, b, acc[j], 0, 0, 0);
        }
    }

    // epilogue: C/D frag row = lhi*4 + r, col = j*16 + l15
    #pragma unroll
    for (int r = 0; r < 4; ++r) {
        const int row = bm + lhi * 4 + r;
        if (row < Nn) {
            float p1 = 0.f, p2 = 0.f;
            #pragma unroll
            for (int j = 0; j < 8; ++j) {
                const int col = j * 16 + l15;
                const float v = acc[j][r];
                Hb[(size_t)row * OUT_DIM + col] = f2bf(v);
                p1 = fmaf(v, av[col], p1);
                p2 = fmaf(v, av[128 + col], p2);
            }
            #pragma unroll
            for (int o = 1; o < 16; o <<= 1) {   // reduce across the 16-lane group
                p1 += __shfl_xor(p1, o);
                p2 += __shfl_xor(p2, o);
            }
            if (l15 == 0) { s1[row] = p1; s2[row] = p2; }
        }
    }
}

// ---------------- bucketed scatter, fused leaky-relu, single uint4 write ----------------
__global__ __launch_bounds__(256) void scatter_kernel(const int* __restrict__ tio,
                                                      const int* __restrict__ adj,
                                                      const float* __restrict__ s1,
                                                      const float* __restrict__ s2,
                                                      int* __restrict__ cursor,
                                                      uint4* __restrict__ e4, int E) {
    const int k = blockIdx.x * 256 + threadIdx.x;
    if (k >= E) return;
    const int t   = tio[k];
    const int src = adj[k];
    const int dst = adj[E + k];
    float ev = s1[src] + s2[dst];
    ev = ev > 0.f ? ev : 0.2f * ev;          // leaky_relu(0.2)
    const int pos = atomicAdd(&cursor[t], 1);
    if (pos < CAP) {
        e4[(size_t)t * CAP + pos] = make_uint4((unsigned)k, (unsigned)dst,
                                               __float_as_uint(ev), 0u);
    }
}

// ---------------- per-row: dedup + softmax + 8-deep pipelined gather + ELU ----------------
// One wave per row: 4096 independent waves, 32 blocks/CU residency.
__device__ __forceinline__ void fma8(float* a, float p, uint4 v) {
    a[0] = fmaf(p, bf2f((unsigned short)(v.x)),       a[0]);
    a[1] = fmaf(p, bf2f((unsigned short)(v.x >> 16)), a[1]);
    a[2] = fmaf(p, bf2f((unsigned short)(v.y)),       a[2]);
    a[3] = fmaf(p, bf2f((unsigned short)(v.y >> 16)), a[3]);
    a[4] = fmaf(p, bf2f((unsigned short)(v.z)),       a[4]);
    a[5] = fmaf(p, bf2f((unsigned short)(v.z >> 16)), a[5]);
    a[6] = fmaf(p, bf2f((unsigned short)(v.w)),       a[6]);
    a[7] = fmaf(p, bf2f((unsigned short)(v.w >> 16)), a[7]);
}

__global__ __launch_bounds__(64) void row_kernel(const int* __restrict__ cursor,
                                                 const uint4* __restrict__ e4,
                                                 const unsigned short* __restrict__ Hb,
                                                 float* __restrict__ out, int Nn) {
    __shared__ int   sh_dst[CAP];
    __shared__ int   sh_kk[CAP];
    __shared__ float sh_p[CAP];
    __shared__ unsigned char sh_act[CAP];
    __shared__ float psum[4][128];
    const int row  = blockIdx.x;
    const int lane = threadIdx.x;
    int cnt = cursor[row];
    if (cnt > CAP) cnt = CAP;
    const size_t base = (size_t)row * CAP;

    for (int i = lane; i < cnt; i += 64) {
        const uint4 v = e4[base + i];
        sh_kk[i]  = (int)v.x;
        sh_dst[i] = (int)v.y;
        sh_p[i]   = __uint_as_float(v.z);
    }
    __syncthreads();

    // dedup (last write wins == max edge index) + row max over active edges
    float lm = -3.0e38f;
    for (int i = lane; i < cnt; i += 64) {
        const int dst = sh_dst[i];
        const int kk  = sh_kk[i];
        bool act = true;
        for (int j = 0; j < cnt; ++j)
            if (sh_dst[j] == dst && sh_kk[j] > kk) { act = false; break; }
        sh_act[i] = act ? 1 : 0;
        if (act) lm = fmaxf(lm, sh_p[i]);
    }
    #pragma unroll
    for (int o = 32; o; o >>= 1) lm = fmaxf(lm, __shfl_xor(lm, o));

    float ls = 0.f;
    for (int i = lane; i < cnt; i += 64) {
        const float p = sh_act[i] ? __expf(sh_p[i] - lm) : 0.f;
        sh_p[i] = p;
        ls += p;
    }
    #pragma unroll
    for (int o = 32; o; o >>= 1) ls += __shfl_xor(ls, o);
    const float inv = (cnt > 0 && ls > 0.f) ? 1.f / ls : 0.f;
    __syncthreads();                       // sh_p updates visible for gather

    // gather: group (lane>>4) takes edges grp, grp+4, grp+8, ... 8 in flight
    const int grp  = lane >> 4;
    const int slot = lane & 15;
    float acc8[8];
    #pragma unroll
    for (int d = 0; d < 8; ++d) acc8[d] = 0.f;

    int j = grp;
    for (; j + 28 < cnt; j += 32) {        // 8 independent gathers in flight
        int   dd[8]; float pp[8];
        #pragma unroll
        for (int u = 0; u < 8; ++u) { dd[u] = sh_dst[j + 4 * u]; pp[u] = sh_p[j + 4 * u]; }
        uint4 vv[8];
        #pragma unroll
        for (int u = 0; u < 8; ++u)
            vv[u] = *(const uint4*)(Hb + (size_t)dd[u] * OUT_DIM + slot * 8);
        #pragma unroll
        for (int u = 0; u < 8; ++u) fma8(acc8, pp[u], vv[u]);
    }
    for (; j < cnt; j += 4) {
        const float p0 = sh_p[j];
        const int   d0 = sh_dst[j];
        const uint4 v0 = *(const uint4*)(Hb + (size_t)d0 * OUT_DIM + slot * 8);
        fma8(acc8, p0, v0);
    }
    *(float4*)&psum[grp][slot * 8]     = make_float4(acc8[0], acc8[1], acc8[2], acc8[3]);
    *(float4*)&psum[grp][slot * 8 + 4] = make_float4(acc8[4], acc8[5], acc8[6], acc8[7]);
    __syncthreads();

    #pragma unroll
    for (int d = lane; d < 128; d += 64) {
        float v = (psum[0][d] + psum[1][d] + psum[2][d] + psum[3][d]) * inv;
        if (cnt == 0) {   // empty row: softmax over all -9e15 -> uniform 1/Nn
            float t = 0.f;
            for (int n = 0; n < Nn; ++n) t += bf2f(Hb[(size_t)n * OUT_DIM + d]);
            v = t / (float)Nn;
        }
        v = v > 0.f ? v : expm1f(v);       // ELU
        out[(size_t)row * OUT_DIM + d] = v;
    }
}

extern "C" void kernel_launch(void* const* d_in, const int* in_sizes, int n_in,
                              void* d_out, int out_size, void* d_ws, size_t ws_size,
                              hipStream_t stream) {
    const float* features = (const float*)d_in[0];
    const int*   adj      = (const int*)d_in[1];   // [2, E]
    const int*   tio      = (const int*)d_in[2];   // [E]
    const float* Wm       = (const float*)d_in[3]; // [256,128]
    const float* av       = (const float*)d_in[4]; // [256]
    float* out = (float*)d_out;

    const int N = in_sizes[0] / IN_DIM;
    const int E = in_sizes[2];
    const int T = out_size / OUT_DIM;

    char* ws = (char*)d_ws;
    unsigned short* Hb = (unsigned short*)ws; ws += (size_t)N * OUT_DIM * 2;
    unsigned short* Wt = (unsigned short*)ws; ws += (size_t)IN_DIM * OUT_DIM * 2;
    float* s1 = (float*)ws;                   ws += (size_t)N * 4;
    float* s2 = (float*)ws;                   ws += (size_t)N * 4;
    int* cursor = (int*)ws;                   ws += (size_t)T * 4;
    uint4* e4 = (uint4*)ws;                   ws += (size_t)T * CAP * 16;

    wt_kernel<<<(IN_DIM * OUT_DIM) / 256, 256, 0, stream>>>(Wm, Wt, cursor, T);
    gemm_h<<<(N + 15) / 16, 64, 0, stream>>>(features, Wt, av, Hb, s1, s2, N);
    scatter_kernel<<<(E + 255) / 256, 256, 0, stream>>>(tio, adj, s1, s2, cursor, e4, E);
    row_kernel<<<T, 64, 0, stream>>>(cursor, e4, Hb, out, N);
}